// Round 1
// baseline (453.956 us; speedup 1.0000x reference)
//
#include <hip/hip_runtime.h>
#include <math.h>

typedef unsigned long long u64;
typedef unsigned int u32;

#define M_ANCH 360000
#define NCLS 80
#define KTOP 1000
#define CAP 2048
#define NBINS 65536
#define RREP 4
#define CONF_THRESH 0.05f
#define NMS_THRESH 0.6f
#define CTR_CLAMP 32.0f
#define SCALE_CLAMP 4.1351665567423560f  /* log(1000/16) */

/* ---- workspace layout (bytes) ---- */
#define HIST_OFF   0u
#define HIST_BYTES (RREP * NBINS * 4u)          /* 1,048,576 */
#define CNT_OFF    (HIST_OFF + HIST_BYTES)      /* 1,048,576 */
#define B_OFF      (CNT_OFF + 4u)               /* 1,048,580 */
#define VW_OFF     (B_OFF + 4u)                 /* 1,048,584 (16 u64 = 128 B) */
#define ZERO_BYTES (VW_OFF + 128u)              /* 1,048,712 */
#define CAND_OFF   ZERO_BYTES                   /* 2048 * 8  */
#define SC_OFF     (CAND_OFF + CAP * 8u)        /* M floats  */
#define CLS_OFF    (SC_OFF + M_ANCH * 4u)       /* M ints    */
#define SSC_OFF    (CLS_OFF + M_ANCH * 4u)      /* 1000 floats */
#define SCLS_OFF   (SSC_OFF + KTOP * 4u)        /* 1000 ints */
#define SUP_OFF    (SCLS_OFF + KTOP * 4u)       /* 16000 u64 */

__device__ __forceinline__ u32 fkey(float f) {
    u32 u = __float_as_uint(f);
    return (u & 0x80000000u) ? ~u : (u | 0x80000000u);
}

/* K1: per-anchor max/argmax over 80 classes, sigmoid, histogram of sort key */
__global__ __launch_bounds__(256) void k_score(const float* __restrict__ cls_pred,
                                               float* __restrict__ sc_all,
                                               int* __restrict__ cls_all,
                                               u32* __restrict__ hist) {
    int i = blockIdx.x * 256 + threadIdx.x;
    if (i >= M_ANCH) return;
    const float4* p = (const float4*)(cls_pred + (size_t)i * NCLS);
    float mv = -1e30f;
    int mc = 0;
#pragma unroll
    for (int q = 0; q < NCLS / 4; q++) {
        float4 v = p[q];
        int c0 = q * 4;
        if (v.x > mv) { mv = v.x; mc = c0; }
        if (v.y > mv) { mv = v.y; mc = c0 + 1; }
        if (v.z > mv) { mv = v.z; mc = c0 + 2; }
        if (v.w > mv) { mv = v.w; mc = c0 + 3; }
    }
    float s = 1.0f / (1.0f + expf(-mv));
    sc_all[i] = s;
    cls_all[i] = mc;
    float m = (s >= CONF_THRESH) ? s : -1.0f;
    u32 u = fkey(m);
    atomicAdd(&hist[((blockIdx.x & (RREP - 1)) << 16) + (u >> 16)], 1u);
}

/* K2: find boundary bin B: bins > B hold < KTOP elements, bins >= B hold >= KTOP */
__global__ __launch_bounds__(1024) void k_scan(u32* __restrict__ hist,
                                               u32* __restrict__ outB) {
    __shared__ u32 csum[1024];
    int t = threadIdx.x;
    int base = t * 64;
    u32 mysum = 0;
#pragma unroll 4
    for (int k = 0; k < 64; k++) {
        u32 b = base + k;
        u32 h = hist[b] + hist[NBINS + b] + hist[2 * NBINS + b] + hist[3 * NBINS + b];
        hist[b] = h;  /* store summed value for the walk below */
        mysum += h;
    }
    csum[t] = mysum;
    __syncthreads();
    u32 v = mysum;
    for (int off = 1; off < 1024; off <<= 1) {
        u32 add = (t + off < 1024) ? csum[t + off] : 0u;
        __syncthreads();
        v += add;
        csum[t] = v;
        __syncthreads();
    }
    u32 A = (t == 1023) ? 0u : csum[t + 1];
    if (A < KTOP && A + mysum >= KTOP) {
        u32 c = A;
        for (int k = 63; k >= 0; k--) {
            u32 b = base + k;
            u32 h = hist[b];
            if (c + h >= KTOP) { outB[0] = b; break; }
            c += h;
        }
    }
}

/* K3: compact candidates (all elements whose key bin >= B) as 64-bit keys */
__global__ __launch_bounds__(256) void k_compact(const float* __restrict__ sc_all,
                                                 const u32* __restrict__ pB,
                                                 u32* __restrict__ counter,
                                                 u64* __restrict__ cand) {
    int i = blockIdx.x * 256 + threadIdx.x;
    if (i >= M_ANCH) return;
    u32 B = *pB;
    float s = sc_all[i];
    float m = (s >= CONF_THRESH) ? s : -1.0f;
    u32 u = fkey(m);
    if ((u >> 16) >= B) {
        u32 pos = atomicAdd(counter, 1u);
        if (pos < CAP) cand[pos] = ((u64)u << 32) | (u64)(0xFFFFFFFFu - (u32)i);
    }
}

/* K4: bitonic sort of candidates (descending), take top 1000, decode boxes */
__global__ __launch_bounds__(1024) void k_select(const u64* __restrict__ cand,
                                                 const u32* __restrict__ counter,
                                                 const float* __restrict__ sc_all,
                                                 const int* __restrict__ cls_all,
                                                 const float* __restrict__ reg_pred,
                                                 const float* __restrict__ anchors,
                                                 float* __restrict__ out,
                                                 float* __restrict__ sel_sc,
                                                 int* __restrict__ sel_cls,
                                                 u64* __restrict__ valid_words) {
    __shared__ u64 keys[CAP];
    int t = threadIdx.x;
    u32 n = *counter;
    if (n > CAP) n = CAP;
    for (int i = t; i < CAP; i += 1024) keys[i] = (i < (int)n) ? cand[i] : 0ull;
    for (int k = 2; k <= CAP; k <<= 1) {
        for (int j = k >> 1; j > 0; j >>= 1) {
            __syncthreads();
            for (int i = t; i < CAP; i += 1024) {
                int ixj = i ^ j;
                if (ixj > i) {
                    u64 a = keys[i], b = keys[ixj];
                    bool desc = ((i & k) == 0);
                    if (desc ? (a < b) : (a > b)) { keys[i] = b; keys[ixj] = a; }
                }
            }
        }
    }
    __syncthreads();
    if (t < KTOP) {
        u64 key = keys[t];
        u32 idx = 0xFFFFFFFFu - (u32)(key & 0xFFFFFFFFull);
        if (idx >= M_ANCH) idx = 0;  /* safety; cannot happen for M >= K */
        float s = sc_all[idx];
        int cl = cls_all[idx];
        float4 a = ((const float4*)anchors)[idx];
        float4 r = ((const float4*)reg_pred)[idx];
        float ox = fminf(fmaxf(r.x * a.z, -CTR_CLAMP), CTR_CLAMP);
        float oy = fminf(fmaxf(r.y * a.w, -CTR_CLAMP), CTR_CLAMP);
        float cx = a.x + ox, cy = a.y + oy;
        float ww = a.z * expf(fminf(r.z, SCALE_CLAMP));
        float hh = a.w * expf(fminf(r.w, SCALE_CLAMP));
        float4 box;
        box.x = cx - 0.5f * ww;
        box.y = cy - 0.5f * hh;
        box.z = cx + 0.5f * ww;
        box.w = cy + 0.5f * hh;
        ((float4*)out)[t] = box;                 /* boxes: out[0..3999] */
        out[5 * KTOP + t] = (float)cl;           /* classes: out[5000..5999] */
        sel_sc[t] = s;
        sel_cls[t] = cl;
        if (s >= CONF_THRESH) atomicOr(&valid_words[t >> 6], 1ull << (t & 63));
    }
}

/* K5: suppression matrix — one wave computes one 64-wide word via ballot */
__global__ __launch_bounds__(256) void k_supmat(const float* __restrict__ out,
                                                const int* __restrict__ sel_cls,
                                                u64* __restrict__ sup) {
    int wid = threadIdx.x >> 6;
    int lane = threadIdx.x & 63;
    int g = blockIdx.x * 4 + wid;          /* g in [0, 16000) */
    int i = g >> 4;
    int w = g & 15;
    int j = w * 64 + lane;
    int jc = (j < KTOP) ? j : (KTOP - 1);
    float4 bi = ((const float4*)out)[i];
    float4 bj = ((const float4*)out)[jc];
    int ci = sel_cls[i], cj = sel_cls[jc];
    float ai = (bi.z - bi.x) * (bi.w - bi.y);
    float aj = (bj.z - bj.x) * (bj.w - bj.y);
    float xx1 = fmaxf(bi.x, bj.x), yy1 = fmaxf(bi.y, bj.y);
    float xx2 = fminf(bi.z, bj.z), yy2 = fminf(bi.w, bj.w);
    float iw = fmaxf(1e-28f, xx2 - xx1), ih = fmaxf(1e-28f, yy2 - yy1);
    float inter = iw * ih;
    float iou = inter / (ai + aj - inter + 1e-14f);
    bool pred = (j < i) && (ci == cj) && (iou > NMS_THRESH);
    u64 bal = __ballot((int)pred);
    if (lane == 0) sup[g] = bal;
}

/* K6: sequential greedy NMS scan, single wave; 16 lanes hold keep-mask words */
#define LOADC(cidx, buf)                                                         \
    {                                                                            \
        _Pragma("unroll") for (int r = 0; r < 16; r++) {                         \
            int row = (cidx)*16 + r;                                             \
            buf[r] = (active && row < KTOP) ? sup[row * 16 + lane] : 0ull;       \
        }                                                                        \
    }

#define PROCC(cidx, buf)                                                         \
    {                                                                            \
        _Pragma("unroll") for (int r = 0; r < 16; r++) {                         \
            int i = (cidx)*16 + r;                                               \
            if (i < KTOP) {                                                      \
                u64 x = buf[r] & keepw;                                          \
                int anysup = __any(x != 0ull);                                   \
                u64 vwv = vws[i >> 6];                                           \
                int vi = (int)((vwv >> (i & 63)) & 1ull);                        \
                int ki = (!anysup) && vi;                                        \
                if (lane == (i >> 6) && ki) keepw |= (1ull << (i & 63));         \
            }                                                                    \
        }                                                                        \
    }

__global__ __launch_bounds__(64) void k_nms(const u64* __restrict__ sup,
                                            const u64* __restrict__ valid_words,
                                            const float* __restrict__ sel_sc,
                                            float* __restrict__ out) {
    __shared__ u64 vws[16];
    __shared__ u64 kw[16];
    int lane = threadIdx.x;
    bool active = lane < 16;
    if (active) vws[lane] = valid_words[lane];
    __syncthreads();
    u64 keepw = 0ull;
    u64 bufA[16], bufB[16];
    const int nChunks = (KTOP + 15) / 16;  /* 63 */
    LOADC(0, bufA);
    for (int c = 0; c < nChunks; c += 2) {
        if (c + 1 < nChunks) LOADC(c + 1, bufB);
        PROCC(c, bufA);
        if (c + 2 < nChunks) LOADC(c + 2, bufA);
        if (c + 1 < nChunks) PROCC(c + 1, bufB);
    }
    if (active) kw[lane] = keepw;
    __syncthreads();
    for (int t = lane; t < KTOP; t += 64) {
        int kb = (int)((kw[t >> 6] >> (t & 63)) & 1ull);
        float s = sel_sc[t];
        out[4 * KTOP + t] = kb ? s : 0.0f;   /* scores*keep: out[4000..4999] */
        out[6 * KTOP + t] = (float)kb;       /* keep:        out[6000..6999] */
    }
}

extern "C" void kernel_launch(void* const* d_in, const int* in_sizes, int n_in,
                              void* d_out, int out_size, void* d_ws, size_t ws_size,
                              hipStream_t stream) {
    const float* cls_pred = (const float*)d_in[0];
    const float* reg_pred = (const float*)d_in[1];
    const float* anchors  = (const float*)d_in[2];
    float* out = (float*)d_out;
    char* ws = (char*)d_ws;

    u32* hist     = (u32*)(ws + HIST_OFF);
    u32* counter  = (u32*)(ws + CNT_OFF);
    u32* pB       = (u32*)(ws + B_OFF);
    u64* vwords   = (u64*)(ws + VW_OFF);
    u64* cand     = (u64*)(ws + CAND_OFF);
    float* sc_all = (float*)(ws + SC_OFF);
    int* cls_all  = (int*)(ws + CLS_OFF);
    float* sel_sc = (float*)(ws + SSC_OFF);
    int* sel_cls  = (int*)(ws + SCLS_OFF);
    u64* sup      = (u64*)(ws + SUP_OFF);

    hipMemsetAsync(d_ws, 0, ZERO_BYTES, stream);

    int nb1 = (M_ANCH + 255) / 256;
    k_score<<<nb1, 256, 0, stream>>>(cls_pred, sc_all, cls_all, hist);
    k_scan<<<1, 1024, 0, stream>>>(hist, pB);
    k_compact<<<nb1, 256, 0, stream>>>(sc_all, pB, counter, cand);
    k_select<<<1, 1024, 0, stream>>>(cand, counter, sc_all, cls_all, reg_pred,
                                     anchors, out, sel_sc, sel_cls, vwords);
    k_supmat<<<(KTOP * 16) / 4, 256, 0, stream>>>(out, sel_cls, sup);
    k_nms<<<1, 64, 0, stream>>>(sup, vwords, sel_sc, out);
}